// Round 10
// baseline (549.065 us; speedup 1.0000x reference)
//
#include <hip/hip_runtime.h>

#define KW 11
#define PAD 5
#define TW 32
#define TH 32
#define IW 42              // TW + KW - 1 (column span incl. halo)
#define VROW 215           // v-result row stride = 5 * 43, ODD (2-way banks: free)
#define VP 43              // moment plane stride inside a row
#define IMH 512
#define IMW 512
#define NBLK 12288         // 16 x 16 x 48

typedef float f2 __attribute__((ext_vector_type(2)));

// vv[r*VROW + m*VP + c]; all LDS b32 (odd strides -> 2 lanes/bank, free).
// Conv packing: (m1,m2) ch-packed, (q11,q22) ch-packed, sx k-pair-packed via
// pre-packed weight pairs wp[j] = {w[j], w[j-1]} (loop-invariant).

template <bool EDGE>
__device__ __forceinline__ void phaseA(
    const float* __restrict__ img1, const float* __restrict__ img2,
    size_t base, int ix0, int iy0, int t, const float* wg, const f2* wp,
    float* __restrict__ vv)
{
    for (int task = t; task < IW * 8; task += 256) {
        const int c  = task % IW;
        const int rg = task / IW;
        const int gc = ix0 + c;
        const int r0 = rg * 4;
        const int gr0 = iy0 + r0;

        f2 m12[4] = {{0,0},{0,0},{0,0},{0,0}};    // (mu1, mu2) per k
        f2 qq[4]  = {{0,0},{0,0},{0,0},{0,0}};    // (x1^2, x2^2) per k
        f2 sxp[2] = {{0,0},{0,0}};                // x1*x2 for k-pairs (0,1),(2,3)
        const bool cvalid = !EDGE || ((gc >= 0) && (gc < IMW));
#pragma unroll
        for (int i = 0; i < 14; ++i) {
            const int gr = gr0 + i;
            f2 x12;
            if (EDGE) {
                const bool ok = cvalid && (gr >= 0) && (gr < IMH);
                const size_t o = base + (size_t)(ok ? gr : 0) * IMW + (ok ? gc : 0);
                x12.x = ok ? img1[o] : 0.f;
                x12.y = ok ? img2[o] : 0.f;
            } else {
                const size_t o = base + (size_t)gr * IMW + gc;
                x12.x = img1[o];
                x12.y = img2[o];
            }
            f2 sq = x12 * x12;
            float sxy = x12.x * x12.y;
            f2 sxy2 = {sxy, sxy};
#pragma unroll
            for (int k = 0; k < 4; ++k) {         // ch-packed m/q convs
                const int j = i - k;
                if (j >= 0 && j < KW) {
                    float w = wg[j];
                    f2 w2 = {w, w};
                    m12[k] += w2 * x12;
                    qq[k]  += w2 * sq;
                }
            }
#pragma unroll
            for (int kp = 0; kp < 2; ++kp) {      // k-pair-packed sx conv
                const int j0 = i - 2 * kp;        // tap for k = 2kp (lo half)
                if (j0 >= 1 && j0 < KW) {
                    sxp[kp] += wp[j0] * sxy2;     // {w[j0], w[j0-1]}
                } else if (j0 == 0) {
                    sxp[kp].x += wg[0] * sxy;
                } else if (j0 == KW) {
                    sxp[kp].y += wg[KW - 1] * sxy;
                }
            }
        }
        const int vb = r0 * VROW + c;
#pragma unroll
        for (int k = 0; k < 4; ++k) {
            vv[vb + k * VROW]          = m12[k].x;
            vv[vb + k * VROW + VP]     = m12[k].y;
            vv[vb + k * VROW + 2 * VP] = qq[k].x;
            vv[vb + k * VROW + 3 * VP] = qq[k].y;
            vv[vb + k * VROW + 4 * VP] = (k & 1) ? sxp[k >> 1].y : sxp[k >> 1].x;
        }
    }
}

__global__ __launch_bounds__(256, 5) void ssim_main(
    const float* __restrict__ img1, const float* __restrict__ img2,
    const float* __restrict__ window, float* __restrict__ partial)
{
    __shared__ float vv[TH * VROW];      // 27.5 KB -> 5 blocks/CU
    __shared__ float g[KW];
    __shared__ float wsum[4];

    const int t = threadIdx.x;

    // Separable 1D Gaussian = row-sums of the 2D window (columns sum to 1).
    if (t < KW) {
        float s = 0.f;
        for (int j = 0; j < KW; ++j) s += window[(t * KW + j) * 3];
        g[t] = s;
    }
    __syncthreads();

    float wg[KW];
#pragma unroll
    for (int j = 0; j < KW; ++j) wg[j] = g[j];   // broadcast: conflict-free
    f2 wp[KW];                                    // wp[j] = {w[j], w[j-1]}, j>=1
    wp[0] = (f2){wg[0], 0.f};
#pragma unroll
    for (int j = 1; j < KW; ++j) wp[j] = (f2){wg[j], wg[j - 1]};

    const int plane = blockIdx.z;
    const size_t base = (size_t)plane * IMH * IMW;
    const int ix0 = blockIdx.x * TW - PAD;
    const int iy0 = blockIdx.y * TH - PAD;

    // ---- Phase A: vertical 11-tap straight from global (lane<->col coalesced).
    const bool interior = (ix0 >= 0) && (ix0 + IW <= IMW) &&
                          (iy0 >= 0) && (iy0 + IW <= IMH);
    if (interior) phaseA<false>(img1, img2, base, ix0, iy0, t, wg, wp, vv);
    else          phaseA<true >(img1, img2, base, ix0, iy0, t, wg, wp, vv);
    __syncthreads();

    // ---- Phase B: horizontal 11-tap + SSIM; 4 adjacent cols per thread.
    const float C1v = 0.0001f;
    const float C2v = 0.0009f;
    const int row = t >> 3;                       // 0..31
    const int qc = t & 7;                         // col quad 0..7
    const float* vp = &vv[row * VROW + qc * 4];
    f2 am12[4] = {{0,0},{0,0},{0,0},{0,0}};
    f2 aqq[4]  = {{0,0},{0,0},{0,0},{0,0}};
    f2 asxp[2] = {{0,0},{0,0}};
#pragma unroll
    for (int cc = 0; cc < 14; ++cc) {
        f2 v12 = {vp[cc],          vp[cc + VP]};
        f2 vqq = {vp[cc + 2 * VP], vp[cc + 3 * VP]};
        float vx = vp[cc + 4 * VP];
        f2 vx2 = {vx, vx};
#pragma unroll
        for (int k = 0; k < 4; ++k) {
            const int j = cc - k;
            if (j >= 0 && j < KW) {
                float w = wg[j];
                f2 w2 = {w, w};
                am12[k] += w2 * v12;
                aqq[k]  += w2 * vqq;
            }
        }
#pragma unroll
        for (int kp = 0; kp < 2; ++kp) {
            const int j0 = cc - 2 * kp;
            if (j0 >= 1 && j0 < KW) {
                asxp[kp] += wp[j0] * vx2;
            } else if (j0 == 0) {
                asxp[kp].x += wg[0] * vx;
            } else if (j0 == KW) {
                asxp[kp].y += wg[KW - 1] * vx;
            }
        }
    }
    float lsum = 0.f;
#pragma unroll
    for (int k = 0; k < 4; ++k) {
        float mu1 = am12[k].x, mu2 = am12[k].y;
        float mu1sq = mu1 * mu1, mu2sq = mu2 * mu2, mu12 = mu1 * mu2;
        float sig1 = aqq[k].x - mu1sq;
        float sig2 = aqq[k].y - mu2sq;
        float sig12 = ((k & 1) ? asxp[k >> 1].y : asxp[k >> 1].x) - mu12;
        float num = (2.f * mu12 + C1v) * (2.f * sig12 + C2v);
        float den = (mu1sq + mu2sq + C1v) * (sig1 + sig2 + C2v);
        float r = __builtin_amdgcn_rcpf(den);
        r = r * (2.f - den * r);                  // Newton -> ~fp32 exact
        lsum += num * r;
    }

    // ---- Reduction: wave shuffle -> cross-wave LDS -> plain per-block store.
#pragma unroll
    for (int off = 32; off > 0; off >>= 1) lsum += __shfl_down(lsum, off, 64);
    if ((t & 63) == 0) wsum[t >> 6] = lsum;
    __syncthreads();
    if (t == 0) {
        unsigned bid = (blockIdx.z * gridDim.y + blockIdx.y) * gridDim.x
                     + blockIdx.x;
        partial[bid] = wsum[0] + wsum[1] + wsum[2] + wsum[3];
    }
}

__global__ __launch_bounds__(256) void ssim_reduce(
    const float* __restrict__ partial, float* __restrict__ out, double inv_n)
{
    __shared__ double dsum[4];
    const int t = threadIdx.x;
    double s = 0.0;
    for (int i = t; i < NBLK; i += 256) s += (double)partial[i];
#pragma unroll
    for (int off = 32; off > 0; off >>= 1) s += __shfl_down(s, off, 64);
    if ((t & 63) == 0) dsum[t >> 6] = s;
    __syncthreads();
    if (t == 0) out[0] = (float)((dsum[0] + dsum[1] + dsum[2] + dsum[3]) * inv_n);
}

extern "C" void kernel_launch(void* const* d_in, const int* in_sizes, int n_in,
                              void* d_out, int out_size, void* d_ws, size_t ws_size,
                              hipStream_t stream) {
    const float* img1   = (const float*)d_in[0];
    const float* img2   = (const float*)d_in[1];
    const float* window = (const float*)d_in[2];
    float* out = (float*)d_out;
    float* partial = (float*)d_ws;               // 12288 floats = 48 KB

    const int nplanes = in_sizes[0] / (IMH * IMW);   // 48
    const long long total = (long long)in_sizes[0];

    dim3 grid(IMW / TW, IMH / TH, nplanes);      // 16 x 16 x 48 = 12288
    ssim_main<<<grid, 256, 0, stream>>>(img1, img2, window, partial);
    ssim_reduce<<<1, 256, 0, stream>>>(partial, out, 1.0 / (double)total);
}

// Round 11
// 177.699 us; speedup vs baseline: 3.0899x; 3.0899x over previous
//
#include <hip/hip_runtime.h>

#define KW 11
#define PAD 5
#define TW 32
#define TH 32
#define IW 42              // TW + KW - 1 (column span incl. halo)
#define VROW 215           // v-result row stride = 5 * 43, ODD (2-way banks: free)
#define VP 43              // moment plane stride inside a row
#define IMH 512
#define IMW 512
#define NBLK 12288         // 16 x 16 x 48

typedef float f2 __attribute__((ext_vector_type(2)));

// vv[r*VROW + m*VP + c]; all LDS b32 (odd strides -> 2 lanes/bank, free).
// Packed-math pairing: (m1,m2) and (q11,q22) share weights -> v_pk_fma_f32.
// NOTE (R10 lesson): never pass pointers to thread-local arrays — forces
// them to scratch (531 MB spill traffic). wg[] here is only used directly.

template <bool EDGE>
__device__ __forceinline__ void phaseA(
    const float* __restrict__ img1, const float* __restrict__ img2,
    size_t base, int ix0, int iy0, int t, const float* wg,
    float* __restrict__ vv)
{
    for (int task = t; task < IW * 8; task += 256) {
        const int c  = task % IW;
        const int rg = task / IW;
        const int gc = ix0 + c;
        const int r0 = rg * 4;
        const int gr0 = iy0 + r0;

        f2 m12[4]  = {{0,0},{0,0},{0,0},{0,0}};   // (mu1, mu2) accumulators
        f2 qq[4]   = {{0,0},{0,0},{0,0},{0,0}};   // (x1^2, x2^2) accumulators
        float sx[4] = {0, 0, 0, 0};               // x1*x2 accumulator
        const bool cvalid = !EDGE || ((gc >= 0) && (gc < IMW));
#pragma unroll
        for (int i = 0; i < 14; ++i) {
            const int gr = gr0 + i;
            f2 x12;
            if (EDGE) {
                const bool ok = cvalid && (gr >= 0) && (gr < IMH);
                const size_t o = base + (size_t)(ok ? gr : 0) * IMW + (ok ? gc : 0);
                x12.x = ok ? img1[o] : 0.f;
                x12.y = ok ? img2[o] : 0.f;
            } else {
                const size_t o = base + (size_t)gr * IMW + gc;
                x12.x = img1[o];
                x12.y = img2[o];
            }
            f2 sq = x12 * x12;                    // packed mul
            float sxy = x12.x * x12.y;
#pragma unroll
            for (int k = 0; k < 4; ++k) {
                const int j = i - k;
                if (j >= 0 && j < KW) {
                    float w = wg[j];
                    f2 w2 = {w, w};
                    m12[k] += w2 * x12;           // v_pk_fma_f32
                    qq[k]  += w2 * sq;            // v_pk_fma_f32
                    sx[k]  += w * sxy;
                }
            }
        }
        const int vb = r0 * VROW + c;
#pragma unroll
        for (int k = 0; k < 4; ++k) {
            vv[vb + k * VROW]          = m12[k].x;
            vv[vb + k * VROW + VP]     = m12[k].y;
            vv[vb + k * VROW + 2 * VP] = qq[k].x;
            vv[vb + k * VROW + 3 * VP] = qq[k].y;
            vv[vb + k * VROW + 4 * VP] = sx[k];
        }
    }
}

__global__ __launch_bounds__(256, 5) void ssim_main(
    const float* __restrict__ img1, const float* __restrict__ img2,
    const float* __restrict__ window, float* __restrict__ partial)
{
    __shared__ float vv[TH * VROW];      // 27.5 KB -> 5 blocks/CU
    __shared__ float g[KW];
    __shared__ float wsum[4];

    const int t = threadIdx.x;

    // Separable 1D Gaussian = row-sums of the 2D window (columns sum to 1).
    if (t < KW) {
        float s = 0.f;
        for (int j = 0; j < KW; ++j) s += window[(t * KW + j) * 3];
        g[t] = s;
    }
    __syncthreads();

    float wg[KW];
#pragma unroll
    for (int j = 0; j < KW; ++j) wg[j] = g[j];   // broadcast: conflict-free

    const int plane = blockIdx.z;
    const size_t base = (size_t)plane * IMH * IMW;
    const int ix0 = blockIdx.x * TW - PAD;
    const int iy0 = blockIdx.y * TH - PAD;

    // ---- Phase A: vertical 11-tap straight from global (lane<->col coalesced).
    // Interior blocks (76.6%) skip all bounds logic (block-uniform branch).
    const bool interior = (ix0 >= 0) && (ix0 + IW <= IMW) &&
                          (iy0 >= 0) && (iy0 + IW <= IMH);
    if (interior) phaseA<false>(img1, img2, base, ix0, iy0, t, wg, vv);
    else          phaseA<true >(img1, img2, base, ix0, iy0, t, wg, vv);
    __syncthreads();

    // ---- Phase B: horizontal 11-tap + SSIM; 4 adjacent cols per thread.
    const float C1v = 0.0001f;
    const float C2v = 0.0009f;
    const int row = t >> 3;                       // 0..31
    const int qc = t & 7;                         // col quad 0..7
    const float* vp = &vv[row * VROW + qc * 4];
    f2 am12[4] = {{0,0},{0,0},{0,0},{0,0}};
    f2 aqq[4]  = {{0,0},{0,0},{0,0},{0,0}};
    float asx[4] = {0, 0, 0, 0};
#pragma unroll
    for (int cc = 0; cc < 14; ++cc) {
        f2 v12 = {vp[cc],          vp[cc + VP]};
        f2 vqq = {vp[cc + 2 * VP], vp[cc + 3 * VP]};
        float vx = vp[cc + 4 * VP];
#pragma unroll
        for (int k = 0; k < 4; ++k) {
            const int j = cc - k;
            if (j >= 0 && j < KW) {
                float w = wg[j];
                f2 w2 = {w, w};
                am12[k] += w2 * v12;              // v_pk_fma_f32
                aqq[k]  += w2 * vqq;              // v_pk_fma_f32
                asx[k]  += w * vx;
            }
        }
    }
    float lsum = 0.f;
#pragma unroll
    for (int k = 0; k < 4; ++k) {
        float mu1 = am12[k].x, mu2 = am12[k].y;
        float mu1sq = mu1 * mu1, mu2sq = mu2 * mu2, mu12 = mu1 * mu2;
        float sig1 = aqq[k].x - mu1sq;
        float sig2 = aqq[k].y - mu2sq;
        float sig12 = asx[k] - mu12;
        float num = (2.f * mu12 + C1v) * (2.f * sig12 + C2v);
        float den = (mu1sq + mu2sq + C1v) * (sig1 + sig2 + C2v);
        float r = __builtin_amdgcn_rcpf(den);
        r = r * (2.f - den * r);                  // Newton -> ~fp32 exact
        lsum += num * r;
    }

    // ---- Reduction: wave shuffle -> cross-wave LDS -> plain per-block store.
#pragma unroll
    for (int off = 32; off > 0; off >>= 1) lsum += __shfl_down(lsum, off, 64);
    if ((t & 63) == 0) wsum[t >> 6] = lsum;
    __syncthreads();
    if (t == 0) {
        unsigned bid = (blockIdx.z * gridDim.y + blockIdx.y) * gridDim.x
                     + blockIdx.x;
        partial[bid] = wsum[0] + wsum[1] + wsum[2] + wsum[3];
    }
}

__global__ __launch_bounds__(256) void ssim_reduce(
    const float* __restrict__ partial, float* __restrict__ out, double inv_n)
{
    __shared__ double dsum[4];
    const int t = threadIdx.x;
    double s = 0.0;
    for (int i = t; i < NBLK; i += 256) s += (double)partial[i];
#pragma unroll
    for (int off = 32; off > 0; off >>= 1) s += __shfl_down(s, off, 64);
    if ((t & 63) == 0) dsum[t >> 6] = s;
    __syncthreads();
    if (t == 0) out[0] = (float)((dsum[0] + dsum[1] + dsum[2] + dsum[3]) * inv_n);
}

extern "C" void kernel_launch(void* const* d_in, const int* in_sizes, int n_in,
                              void* d_out, int out_size, void* d_ws, size_t ws_size,
                              hipStream_t stream) {
    const float* img1   = (const float*)d_in[0];
    const float* img2   = (const float*)d_in[1];
    const float* window = (const float*)d_in[2];
    float* out = (float*)d_out;
    float* partial = (float*)d_ws;               // 12288 floats = 48 KB

    const int nplanes = in_sizes[0] / (IMH * IMW);   // 48
    const long long total = (long long)in_sizes[0];

    dim3 grid(IMW / TW, IMH / TH, nplanes);      // 16 x 16 x 48 = 12288
    ssim_main<<<grid, 256, 0, stream>>>(img1, img2, window, partial);
    ssim_reduce<<<1, 256, 0, stream>>>(partial, out, 1.0 / (double)total);
}